// Round 17
// baseline (250.853 us; speedup 1.0000x reference)
//
#include <hip/hip_runtime.h>
#include <cstddef>
#include <cstdint>

typedef short  bf16x8 __attribute__((ext_vector_type(8)));
typedef float  f32x16 __attribute__((ext_vector_type(16)));
typedef float  f32x4  __attribute__((ext_vector_type(4)));   // for nontemporal

#define IC 2048
#define JD 16
#define NC 64
#define DD 32

// ---------------------------------------------------------------- helpers ---
__device__ __forceinline__ unsigned f2bf1(float f) {          // RNE f32->bf16
  unsigned u = __float_as_uint(f);
  return (u + 0x7FFFu + ((u >> 16) & 1u)) >> 16;
}
__device__ __forceinline__ unsigned pk2(float lo, float hi) { // 2 bf16 in u32
  return f2bf1(lo) | (f2bf1(hi) << 16);
}
__device__ __forceinline__ float bflo(unsigned v) { return __uint_as_float(v << 16); }
__device__ __forceinline__ float bfhi(unsigned v) { return __uint_as_float(v & 0xFFFF0000u); }

template<int CTRL>
__device__ __forceinline__ float dpp_mov_f(float v) {
  int x = __builtin_amdgcn_mov_dpp(__float_as_int(v), CTRL, 0xf, 0xf, true);
  return __int_as_float(x);
}
__device__ __forceinline__ float row16_sum(float v) {
  v += dpp_mov_f<0x121>(v);
  v += dpp_mov_f<0x122>(v);
  v += dpp_mov_f<0x124>(v);
  v += dpp_mov_f<0x128>(v);
  return v;
}

// ===================================================== streaming MFMA path ==
// Wb fragment-order: row r = n*IC+i (131072 rows x 512 ushort = 1KB).
// Lane l's granule Wb[r*512 + l*8 .. +8] = bf16 W[n][i][d=l&31][j=(l>>5)*8..+8].
// xb: same per-row fragment order for x: row i, lane l -> x[b=l&31][i][j=...].
// Vb2: [n][dc(0..7)][b(0..31)][4] bf16 (dc = d/4) -> contiguous dot loads.
// denP: [i][half(2)][b] f32 partial softmax denominators. accum recomputes e
// from its own u with the IDENTICAL FMA sequence -> bit-identical c.

// x -> xb (4 MB -> 2 MB), one granule per thread. grid 512 x 256.
__global__ __launch_bounds__(256) void xb_conv(
    const float* __restrict__ x, unsigned short* __restrict__ xb)
{
  int gid = blockIdx.x * 256 + threadIdx.x;      // 131072
  int i = gid >> 6, l = gid & 63;
  const float* xs = x + ((size_t)(l & 31) * IC + i) * JD + (l >> 5) * 8;
  float4 a = *reinterpret_cast<const float4*>(xs);
  float4 b = *reinterpret_cast<const float4*>(xs + 4);
  uint4 p;
  p.x = pk2(a.x, a.y); p.y = pk2(a.z, a.w);
  p.z = pk2(b.x, b.y); p.w = pk2(b.z, b.w);
  *reinterpret_cast<uint4*>(xb + (size_t)i * 512 + l * 8) = p;
}

// FUSED: W f32 -> Wb bf16 conversion + round-0 accumulation (c = 1/64 exact).
// R17: W reads nontemporal via native ext_vector f32x4 (R16 compile fix).
__global__ __launch_bounds__(256) void caps_conv0(
    const unsigned short* __restrict__ xb, const float* __restrict__ Wf,
    unsigned short* __restrict__ Wb, float* __restrict__ sPart)
{
  const int t = threadIdx.x, w = t >> 6, l = t & 63;
  const int m = l & 31, h = l >> 5;
  const int Wv = blockIdx.x * 4 + w;             // 0..4095
  const int n = Wv & 63, ch = Wv >> 6;
  const int i0 = ch * 32;
  const int ld   = ((l & 1) << 5) | (l >> 1);
  const int srci = (((l & 31) << 1) | (l >> 5)) << 2;   // byte addr for bperm
  const float* wrow = Wf + ((size_t)n * IC + i0) * 512 + (size_t)l * 8;
  unsigned short* wbrow = Wb + ((size_t)n * IC + i0) * 512 + (size_t)ld * 8;
  const unsigned short* xrow = xb + (size_t)i0 * 512 + l * 8;
  f32x16 sacc = (f32x16)0.0f;
#pragma unroll 4
  for (int ii = 0; ii < 32; ++ii) {
    f32x4 a = __builtin_nontemporal_load(
        reinterpret_cast<const f32x4*>(wrow + (size_t)ii * 512));
    f32x4 b = __builtin_nontemporal_load(
        reinterpret_cast<const f32x4*>(wrow + (size_t)ii * 512 + 4));
    uint4 p;
    p.x = pk2(a.x, a.y); p.y = pk2(a.z, a.w);
    p.z = pk2(b.x, b.y); p.w = pk2(b.z, b.w);
    *reinterpret_cast<uint4*>(wbrow + (size_t)ii * 512) = p;   // frag-order Wb
    uint4 af;                                     // pull my fragment
    af.x = (unsigned)__builtin_amdgcn_ds_bpermute(srci, (int)p.x);
    af.y = (unsigned)__builtin_amdgcn_ds_bpermute(srci, (int)p.y);
    af.z = (unsigned)__builtin_amdgcn_ds_bpermute(srci, (int)p.z);
    af.w = (unsigned)__builtin_amdgcn_ds_bpermute(srci, (int)p.w);
    bf16x8 bf = *reinterpret_cast<const bf16x8*>(xrow + (size_t)ii * 512);
    sacc = __builtin_amdgcn_mfma_f32_32x32x16_bf16(
        *reinterpret_cast<bf16x8*>(&af), bf, sacc, 0, 0, 0);
  }
  float* page = sPart + ((size_t)n * 64 + ch) * 1024;   // [dc][b][4] = 4 KB
#pragma unroll
  for (int q = 0; q < 4; ++q) {
    float4 v = make_float4(sacc[4*q] * 0.015625f, sacc[4*q+1] * 0.015625f,
                           sacc[4*q+2] * 0.015625f, sacc[4*q+3] * 0.015625f);
    *reinterpret_cast<float4*>(page + ((2*q+h) * 32 + m) * 4) = v;
  }
}

// den pass (r>=1): wave owns (i, n-half of 32). nn processed in pairs with
// named prefetch regs -> 2+ KB in flight/wave, 2 independent MFMAs. pden add
// order UNCHANGED -> denP bit-identical to R15.
__global__ __launch_bounds__(256) void caps_den(
    const unsigned short* __restrict__ xb, const unsigned short* __restrict__ Wb,
    const unsigned short* __restrict__ Vb2, float* __restrict__ denP)
{
  const int t = threadIdx.x, w = t >> 6, l = t & 63;
  const int m = l & 31, h = l >> 5;
  const int Wv = blockIdx.x * 4 + w;             // 0..4095
  const int i = Wv >> 1, half = Wv & 1;
  const int n0 = half * 32;
  bf16x8 bfrag = *reinterpret_cast<const bf16x8*>(xb + (size_t)i * 512 + l * 8);
  const unsigned short* wbase = Wb + ((size_t)n0 * IC + i) * 512 + l * 8;
  const size_t nstr = (size_t)IC * 512;          // row stride per n
  float pden = 0.f;
  bf16x8 afA = *reinterpret_cast<const bf16x8*>(wbase);
  bf16x8 afB = *reinterpret_cast<const bf16x8*>(wbase + nstr);
#pragma unroll
  for (int nn = 0; nn < 32; nn += 2) {
    bf16x8 nfA, nfB;
    if (nn + 2 < 32) {
      nfA = *reinterpret_cast<const bf16x8*>(wbase + (size_t)(nn + 2) * nstr);
      nfB = *reinterpret_cast<const bf16x8*>(wbase + (size_t)(nn + 3) * nstr);
    }
    f32x16 uA = __builtin_amdgcn_mfma_f32_32x32x16_bf16(
        afA, bfrag, (f32x16)0.0f, 0, 0, 0);
    f32x16 uB = __builtin_amdgcn_mfma_f32_32x32x16_bf16(
        afB, bfrag, (f32x16)0.0f, 0, 0, 0);
    {
      const int n = n0 + nn;
      float partial = 0.f;
      const unsigned short* vr = Vb2 + (size_t)n * 1024;
#pragma unroll
      for (int q = 0; q < 4; ++q) {
        uint2 vv = *reinterpret_cast<const uint2*>(vr + ((2*q+h) * 32 + m) * 4);
        partial += bflo(vv.x) * uA[4*q+0] + bfhi(vv.x) * uA[4*q+1]
                 + bflo(vv.y) * uA[4*q+2] + bfhi(vv.y) * uA[4*q+3];
      }
      float logit = partial + __shfl_xor(partial, 32);
      pden += __expf(logit);
    }
    {
      const int n = n0 + nn + 1;
      float partial = 0.f;
      const unsigned short* vr = Vb2 + (size_t)n * 1024;
#pragma unroll
      for (int q = 0; q < 4; ++q) {
        uint2 vv = *reinterpret_cast<const uint2*>(vr + ((2*q+h) * 32 + m) * 4);
        partial += bflo(vv.x) * uB[4*q+0] + bfhi(vv.x) * uB[4*q+1]
                 + bflo(vv.y) * uB[4*q+2] + bfhi(vv.y) * uB[4*q+3];
      }
      float logit = partial + __shfl_xor(partial, 32);
      pden += __expf(logit);
    }
    afA = nfA; afB = nfB;
  }
  if (h == 0) denP[(size_t)i * 64 + half * 32 + m] = pden;
}

// accum r1/r2: weighted GEMM; e recomputed LOCALLY (same FMA order as den ->
// bit-identical c). Vb2 loads hoisted out of the loop (loop-invariant).
__global__ __launch_bounds__(256) void caps_accum(
    const unsigned short* __restrict__ xb, const unsigned short* __restrict__ Wb,
    const unsigned short* __restrict__ Vb2, const float* __restrict__ denP,
    float* __restrict__ sPart)
{
  const int t = threadIdx.x, w = t >> 6, l = t & 63;
  const int m = l & 31, h = l >> 5;
  const int Wv = blockIdx.x * 4 + w;             // 0..4095
  const int n = Wv & 63, ch = Wv >> 6;
  const int i0 = ch * 32;
  const unsigned short* wrow = Wb + ((size_t)n * IC + i0) * 512 + l * 8;
  const unsigned short* xrow = xb + (size_t)i0 * 512 + l * 8;
  const unsigned short* vr = Vb2 + (size_t)n * 1024;
  uint2 vv0 = *reinterpret_cast<const uint2*>(vr + ((0 + h) * 32 + m) * 4);
  uint2 vv1 = *reinterpret_cast<const uint2*>(vr + ((2 + h) * 32 + m) * 4);
  uint2 vv2 = *reinterpret_cast<const uint2*>(vr + ((4 + h) * 32 + m) * 4);
  uint2 vv3 = *reinterpret_cast<const uint2*>(vr + ((6 + h) * 32 + m) * 4);
  f32x16 sacc = (f32x16)0.0f;
#pragma unroll 4
  for (int ii = 0; ii < 32; ++ii) {
    bf16x8 af = *reinterpret_cast<const bf16x8*>(wrow + (size_t)ii * 512);
    bf16x8 bf = *reinterpret_cast<const bf16x8*>(xrow + (size_t)ii * 512);
    f32x16 u = __builtin_amdgcn_mfma_f32_32x32x16_bf16(
        af, bf, (f32x16)0.0f, 0, 0, 0);
    // recompute e with the SAME dot sequence as caps_den (lane m = b)
    float partial = 0.f;
    partial += bflo(vv0.x) * u[0]  + bfhi(vv0.x) * u[1]
             + bflo(vv0.y) * u[2]  + bfhi(vv0.y) * u[3];
    partial += bflo(vv1.x) * u[4]  + bfhi(vv1.x) * u[5]
             + bflo(vv1.y) * u[6]  + bfhi(vv1.y) * u[7];
    partial += bflo(vv2.x) * u[8]  + bfhi(vv2.x) * u[9]
             + bflo(vv2.y) * u[10] + bfhi(vv2.y) * u[11];
    partial += bflo(vv3.x) * u[12] + bfhi(vv3.x) * u[13]
             + bflo(vv3.y) * u[14] + bfhi(vv3.y) * u[15];
    float logit = partial + __shfl_xor(partial, 32);
    float e = __expf(logit);
    float dp = denP[(size_t)(i0 + ii) * 64 + m]
             + denP[(size_t)(i0 + ii) * 64 + 32 + m];
    float c = e / dp;
#pragma unroll
    for (int k = 0; k < 16; ++k) sacc[k] += c * u[k];
  }
  float* page = sPart + ((size_t)n * 64 + ch) * 1024;
#pragma unroll
  for (int q = 0; q < 4; ++q) {
    float4 v = make_float4(sacc[4*q], sacc[4*q+1], sacc[4*q+2], sacc[4*q+3]);
    *reinterpret_cast<float4*>(page + ((2*q+h) * 32 + m) * 4) = v;
  }
}

// fused 64-page reduce + squash; emits V (f32), Vb2 (bf16) or out.
// 256 blocks (n x b-octet) x 64 thr; s2 reduce over dc via shfl_xor.
__global__ __launch_bounds__(64) void caps_redsq(
    const float4* __restrict__ sPart, float* __restrict__ V,
    unsigned short* __restrict__ Vb2, float* __restrict__ out, int mode)
{
  const int n = blockIdx.x >> 2, bq = blockIdx.x & 3;
  const int t = threadIdx.x;               // 64 = dc(8) x b8(8)
  const int dc = t >> 3, b8 = t & 7;
  const int b = bq * 8 + b8;
  const float4* base = sPart + (size_t)n * 64 * 256 + dc * 32 + b;
  float4 a = make_float4(0.f, 0.f, 0.f, 0.f);
#pragma unroll 8
  for (int ch = 0; ch < 64; ++ch) {
    float4 v = base[(size_t)ch * 256];
    a.x += v.x; a.y += v.y; a.z += v.z; a.w += v.w;
  }
  float s2 = a.x*a.x + a.y*a.y + a.z*a.z + a.w*a.w;
  s2 += __shfl_xor(s2, 8);
  s2 += __shfl_xor(s2, 16);
  s2 += __shfl_xor(s2, 32);
  float scale = s2 / ((1.0f + s2) * sqrtf(s2 + 1e-7f));
  float4 vd = make_float4(a.x*scale, a.y*scale, a.z*scale, a.w*scale);
  const size_t off = ((size_t)b * NC + n) * DD + dc * 4;   // V/out [b][n][d]
  if (mode == 2) {
    *reinterpret_cast<float4*>(out + off) = vd;
  } else {
    float4 nv = vd;
    if (mode == 1) {
      float4 old = *reinterpret_cast<const float4*>(V + off);
      nv.x += old.x; nv.y += old.y; nv.z += old.z; nv.w += old.w;
    }
    *reinterpret_cast<float4*>(V + off) = nv;
    uint2 pb;
    pb.x = pk2(nv.x, nv.y);
    pb.y = pk2(nv.z, nv.w);
    *reinterpret_cast<uint2*>(Vb2 + (size_t)n * 1024 + (dc * 32 + b) * 4) = pb;
  }
}

// ============================== fallback: R6 f32 path (ws too small) ========
__global__ void fb_zero(float* __restrict__ s) {
  s[blockIdx.x * 256 + threadIdx.x] = 0.0f;
}
__global__ __launch_bounds__(1024, 4)
void fb_pass(const float* __restrict__ x, const float* __restrict__ W,
             const float* __restrict__ V, float* __restrict__ sOut,
             float* __restrict__ sPart, int r, int usePart)
{
  const int t = threadIdx.x, w = t >> 6, l = t & 63;
  const int n = (w << 2) | (l >> 4);
  const int d0 = (l & 15) << 1;
  const int blk = blockIdx.x, xcd = blk & 7, slot = blk >> 3;
  const int ic = xcd * 8 + (slot >> 3), bq = slot & 7;
  const int i0 = ic * 32, bbase = bq * 4;
  __shared__ float den[2][4];
  __shared__ float Vlds[4 * NC * DD];
  if (r != 0) {
    const float4* src = reinterpret_cast<const float4*>(V + (size_t)bbase * 2048);
    float4* dst = reinterpret_cast<float4*>(Vlds);
    dst[t] = src[t]; dst[t + 1024] = src[t + 1024];
  }
  float acc0[4], acc1[4];
#pragma unroll
  for (int b = 0; b < 4; ++b) { acc0[b] = 0.f; acc1[b] = 0.f; }
  for (int ii = 0; ii < 32; ++ii) {
    const int i = i0 + ii, p = ii & 1;
    const float4* Wp = reinterpret_cast<const float4*>(
        W + (((size_t)n * IC + i) * DD + d0) * JD);
    float4 wr[8];
#pragma unroll
    for (int q = 0; q < 8; ++q) wr[q] = Wp[q];
    if (r == 0) {
#pragma unroll
      for (int bb = 0; bb < 4; ++bb) {
        const float* xp = x + ((size_t)(bbase + bb) * IC + i) * JD;
        float u0 = 0.f, u1 = 0.f;
#pragma unroll
        for (int q = 0; q < 4; ++q) {
          float4 w0 = wr[q], w1 = wr[4 + q];
          float x0 = xp[4*q], x1 = xp[4*q+1], x2 = xp[4*q+2], x3 = xp[4*q+3];
          u0 += w0.x*x0 + w0.y*x1 + w0.z*x2 + w0.w*x3;
          u1 += w1.x*x0 + w1.y*x1 + w1.z*x2 + w1.w*x3;
        }
        acc0[bb] += u0 * 0.015625f; acc1[bb] += u1 * 0.015625f;
      }
    } else {
      if (t < 4) den[p][t] = 0.0f;
      __syncthreads();
      float p0a[4], p1a[4];
#pragma unroll
      for (int bb = 0; bb < 4; ++bb) {
        const float* xp = x + ((size_t)(bbase + bb) * IC + i) * JD;
        float u0 = 0.f, u1 = 0.f;
#pragma unroll
        for (int q = 0; q < 4; ++q) {
          float4 w0 = wr[q], w1 = wr[4 + q];
          float x0 = xp[4*q], x1 = xp[4*q+1], x2 = xp[4*q+2], x3 = xp[4*q+3];
          u0 += w0.x*x0 + w0.y*x1 + w0.z*x2 + w0.w*x3;
          u1 += w1.x*x0 + w1.y*x1 + w1.z*x2 + w1.w*x3;
        }
        const float2 vv = *reinterpret_cast<const float2*>(
            &Vlds[((size_t)bb * NC + n) * DD + d0]);
        float lp = u0 * vv.x + u1 * vv.y;
        float logit = row16_sum(lp);
        float e = __expf(logit);
        p0a[bb] = e * u0; p1a[bb] = e * u1;
        float es = e + __shfl_xor(e, 16);
        es += __shfl_xor(es, 32);
        if (l == 0) atomicAdd(&den[p][bb], es);
      }
      __syncthreads();
#pragma unroll
      for (int bb = 0; bb < 4; ++bb) {
        float rd = 1.0f / den[p][bb];
        acc0[bb] += p0a[bb] * rd; acc1[bb] += p1a[bb] * rd;
      }
    }
  }
  if (usePart) {
#pragma unroll
    for (int bb = 0; bb < 4; ++bb) {
      float2 v2 = make_float2(acc0[bb], acc1[bb]);
      size_t off = (((size_t)(bq * 64 + ic) * 4 + bb) * NC + n) * DD + d0;
      *reinterpret_cast<float2*>(sPart + off) = v2;
    }
  } else {
#pragma unroll
    for (int bb = 0; bb < 4; ++bb) {
      float* sp = sOut + ((size_t)(bbase + bb) * NC + n) * DD + d0;
      atomicAdd(sp, acc0[bb]); atomicAdd(sp + 1, acc1[bb]);
    }
  }
}
__global__ void fb_reduceS(const float4* __restrict__ sPart, float4* __restrict__ s) {
  int q = blockIdx.x * 256 + threadIdx.x;
  int bq = q >> 11, qq = q & 2047;
  float4 sum = make_float4(0.f, 0.f, 0.f, 0.f);
#pragma unroll 8
  for (int p = 0; p < 64; ++p) {
    float4 v = sPart[(size_t)(bq * 64 + p) * 2048 + qq];
    sum.x += v.x; sum.y += v.y; sum.z += v.z; sum.w += v.w;
  }
  s[q] = sum;
}
__global__ void fb_squash(const float* __restrict__ s, float* __restrict__ V,
                          float* __restrict__ out, int mode)
{
  const int t = threadIdx.x;
  const int g = blockIdx.x * 8 + (t >> 5);
  const int d = t & 31;
  float v = s[(size_t)g * DD + d];
  float s2 = v * v;
#pragma unroll
  for (int off = 16; off; off >>= 1) s2 += __shfl_xor(s2, off);
  float scale = s2 / ((1.0f + s2) * sqrtf(s2 + 1e-7f));
  float vd = scale * v;
  if (mode == 2)      out[(size_t)g * DD + d] = vd;
  else if (mode == 0) V[(size_t)g * DD + d] = vd;
  else                V[(size_t)g * DD + d] += vd;
}

// ---------------------------------------------------------------------------
extern "C" void kernel_launch(void* const* d_in, const int* in_sizes, int n_in,
                              void* d_out, int out_size, void* d_ws, size_t ws_size,
                              hipStream_t stream) {
  const float* x = (const float*)d_in[0];
  const float* W = (const float*)d_in[1];
  float* out = (float*)d_out;
  char* ws = (char*)d_ws;
  // Wb 134217728 | xb 2097152 | denP 524288 | sPart 16777216 | V 262144
  // Vb2 131072  => 154009600
  const size_t NEED_NEW = 154009600ull;

  if (ws_size >= NEED_NEW) {
    unsigned short* Wb  = (unsigned short*)ws;
    unsigned short* xb  = (unsigned short*)(ws + 134217728);
    float* denP         = (float*)(ws + 136314880);
    float* sPart        = (float*)(ws + 136839168);
    float* V            = (float*)(ws + 153616384);
    unsigned short* Vb2 = (unsigned short*)(ws + 153878528);

    xb_conv<<<512, 256, 0, stream>>>(x, xb);
    caps_conv0<<<1024, 256, 0, stream>>>(xb, W, Wb, sPart);   // conv + round 0
    caps_redsq<<<256, 64, 0, stream>>>((const float4*)sPart, V, Vb2, out, 0);
    for (int r = 1; r < 3; ++r) {
      caps_den<<<1024, 256, 0, stream>>>(xb, Wb, Vb2, denP);
      caps_accum<<<1024, 256, 0, stream>>>(xb, Wb, Vb2, denP, sPart);
      caps_redsq<<<256, 64, 0, stream>>>((const float4*)sPart, V, Vb2, out,
                                         r == 2 ? 2 : 1);
    }
  } else {
    float* s     = (float*)ws;
    float* V     = s + 65536;
    float* sPart = V + 65536;
    const size_t need1 = (2ull * 65536 + 512ull * 8192) * 4;
    const int usePart = (ws_size >= need1) ? 1 : 0;
    for (int r = 0; r < 3; ++r) {
      if (!usePart) fb_zero<<<256, 256, 0, stream>>>(s);
      fb_pass<<<512, 1024, 0, stream>>>(x, W, V, s, sPart, r, usePart);
      if (usePart)
        fb_reduceS<<<64, 256, 0, stream>>>((const float4*)sPart, (float4*)s);
      fb_squash<<<256, 256, 0, stream>>>(s, V, out, r == 2 ? 2 : (r == 0 ? 0 : 1));
    }
  }
}

// Round 18
// 229.295 us; speedup vs baseline: 1.0940x; 1.0940x over previous
//
#include <hip/hip_runtime.h>
#include <cstddef>
#include <cstdint>

typedef short  bf16x8 __attribute__((ext_vector_type(8)));
typedef float  f32x16 __attribute__((ext_vector_type(16)));

#define IC 2048
#define JD 16
#define NC 64
#define DD 32

// ---------------------------------------------------------------- helpers ---
__device__ __forceinline__ unsigned f2bf1(float f) {          // RNE f32->bf16
  unsigned u = __float_as_uint(f);
  return (u + 0x7FFFu + ((u >> 16) & 1u)) >> 16;
}
__device__ __forceinline__ unsigned pk2(float lo, float hi) { // 2 bf16 in u32
  return f2bf1(lo) | (f2bf1(hi) << 16);
}
__device__ __forceinline__ float bflo(unsigned v) { return __uint_as_float(v << 16); }
__device__ __forceinline__ float bfhi(unsigned v) { return __uint_as_float(v & 0xFFFF0000u); }

template<int CTRL>
__device__ __forceinline__ float dpp_mov_f(float v) {
  int x = __builtin_amdgcn_mov_dpp(__float_as_int(v), CTRL, 0xf, 0xf, true);
  return __int_as_float(x);
}
__device__ __forceinline__ float row16_sum(float v) {
  v += dpp_mov_f<0x121>(v);
  v += dpp_mov_f<0x122>(v);
  v += dpp_mov_f<0x124>(v);
  v += dpp_mov_f<0x128>(v);
  return v;
}

// ===================================================== streaming MFMA path ==
// Wb fragment-order: row r = n*IC+i (131072 rows x 512 ushort = 1KB).
// Lane l's granule Wb[r*512 + l*8 .. +8] = bf16 W[n][i][d=l&31][j=(l>>5)*8..+8].
// xb: same per-row fragment order for x: row i, lane l -> x[b=l&31][i][j=...].
// Vb2: [n][dc(0..7)][b(0..31)][4] bf16 (dc = d/4) -> contiguous dot loads.
// denP: [i][half(2)][b] f32 partial softmax denominators. accum recomputes e
// from its own u with the IDENTICAL FMA sequence -> bit-identical c.

// x -> xb (4 MB -> 2 MB), one granule per thread. grid 512 x 256.
__global__ __launch_bounds__(256) void xb_conv(
    const float* __restrict__ x, unsigned short* __restrict__ xb)
{
  int gid = blockIdx.x * 256 + threadIdx.x;      // 131072
  int i = gid >> 6, l = gid & 63;
  const float* xs = x + ((size_t)(l & 31) * IC + i) * JD + (l >> 5) * 8;
  float4 a = *reinterpret_cast<const float4*>(xs);
  float4 b = *reinterpret_cast<const float4*>(xs + 4);
  uint4 p;
  p.x = pk2(a.x, a.y); p.y = pk2(a.z, a.w);
  p.z = pk2(b.x, b.y); p.w = pk2(b.z, b.w);
  *reinterpret_cast<uint4*>(xb + (size_t)i * 512 + l * 8) = p;
}

// FUSED: W f32 -> Wb bf16 conversion + round-0 accumulation (c = 1/64 exact).
// Wave owns (n, i-chunk of 32): W f32 read CONTIGUOUS (lane l -> row+l*32B),
// Wb store = within-1KB permuted 16B/lane, own MFMA A-frag via 4 ds_bpermute
// pulls from lane src(l) (inverse of the store perm). sacc chained.
// grid 1024 x 256 = 4096 waves. No barriers, no LDS arrays.
__global__ __launch_bounds__(256) void caps_conv0(
    const unsigned short* __restrict__ xb, const float* __restrict__ Wf,
    unsigned short* __restrict__ Wb, float* __restrict__ sPart)
{
  const int t = threadIdx.x, w = t >> 6, l = t & 63;
  const int m = l & 31, h = l >> 5;
  const int Wv = blockIdx.x * 4 + w;             // 0..4095
  const int n = Wv & 63, ch = Wv >> 6;
  const int i0 = ch * 32;
  const int ld   = ((l & 1) << 5) | (l >> 1);
  const int srci = (((l & 31) << 1) | (l >> 5)) << 2;   // byte addr for bperm
  const float* wrow = Wf + ((size_t)n * IC + i0) * 512 + (size_t)l * 8;
  unsigned short* wbrow = Wb + ((size_t)n * IC + i0) * 512 + (size_t)ld * 8;
  const unsigned short* xrow = xb + (size_t)i0 * 512 + l * 8;
  f32x16 sacc = (f32x16)0.0f;
#pragma unroll 4
  for (int ii = 0; ii < 32; ++ii) {
    float4 a = *reinterpret_cast<const float4*>(wrow + (size_t)ii * 512);
    float4 b = *reinterpret_cast<const float4*>(wrow + (size_t)ii * 512 + 4);
    uint4 p;
    p.x = pk2(a.x, a.y); p.y = pk2(a.z, a.w);
    p.z = pk2(b.x, b.y); p.w = pk2(b.z, b.w);
    *reinterpret_cast<uint4*>(wbrow + (size_t)ii * 512) = p;   // frag-order Wb
    uint4 af;                                     // pull my fragment
    af.x = (unsigned)__builtin_amdgcn_ds_bpermute(srci, (int)p.x);
    af.y = (unsigned)__builtin_amdgcn_ds_bpermute(srci, (int)p.y);
    af.z = (unsigned)__builtin_amdgcn_ds_bpermute(srci, (int)p.z);
    af.w = (unsigned)__builtin_amdgcn_ds_bpermute(srci, (int)p.w);
    bf16x8 bf = *reinterpret_cast<const bf16x8*>(xrow + (size_t)ii * 512);
    sacc = __builtin_amdgcn_mfma_f32_32x32x16_bf16(
        *reinterpret_cast<bf16x8*>(&af), bf, sacc, 0, 0, 0);
  }
  float* page = sPart + ((size_t)n * 64 + ch) * 1024;   // [dc][b][4] = 4 KB
#pragma unroll
  for (int q = 0; q < 4; ++q) {
    float4 v = make_float4(sacc[4*q] * 0.015625f, sacc[4*q+1] * 0.015625f,
                           sacc[4*q+2] * 0.015625f, sacc[4*q+3] * 0.015625f);
    *reinterpret_cast<float4*>(page + ((2*q+h) * 32 + m) * 4) = v;
  }
}

// den pass (r>=1): wave owns (i, n-half of 32). Barrier-free stream of 32
// contiguous 1KB afrag rows; stores ONLY the per-half den partial.
// grid 1024 x 256 (4 waves) = 4096 waves.
__global__ __launch_bounds__(256) void caps_den(
    const unsigned short* __restrict__ xb, const unsigned short* __restrict__ Wb,
    const unsigned short* __restrict__ Vb2, float* __restrict__ denP)
{
  const int t = threadIdx.x, w = t >> 6, l = t & 63;
  const int m = l & 31, h = l >> 5;
  const int Wv = blockIdx.x * 4 + w;             // 0..4095
  const int i = Wv >> 1, half = Wv & 1;
  const int n0 = half * 32;
  bf16x8 bfrag = *reinterpret_cast<const bf16x8*>(xb + (size_t)i * 512 + l * 8);
  float pden = 0.f;
#pragma unroll 2
  for (int nn = 0; nn < 32; ++nn) {
    const int n = n0 + nn;
    bf16x8 af = *reinterpret_cast<const bf16x8*>(
        Wb + ((size_t)n * IC + i) * 512 + l * 8);        // contiguous 1KB/wave
    f32x16 u = __builtin_amdgcn_mfma_f32_32x32x16_bf16(
        af, bfrag, (f32x16)0.0f, 0, 0, 0);
    float partial = 0.f;
    const unsigned short* vr = Vb2 + (size_t)n * 1024;
#pragma unroll
    for (int q = 0; q < 4; ++q) {                // contiguous 256B per chunk
      uint2 vv = *reinterpret_cast<const uint2*>(vr + ((2*q+h) * 32 + m) * 4);
      partial += bflo(vv.x) * u[4*q+0] + bfhi(vv.x) * u[4*q+1]
               + bflo(vv.y) * u[4*q+2] + bfhi(vv.y) * u[4*q+3];
    }
    float logit = partial + __shfl_xor(partial, 32);
    // |logit| small (V squashed): exp safe w/o max-sub; shift-invariant.
    pden += __expf(logit);
  }
  if (h == 0) denP[(size_t)i * 64 + half * 32 + m] = pden;
}

// accum r1/r2: weighted GEMM; e recomputed LOCALLY from u (identical FMA
// order as caps_den -> bit-identical c). Wave owns (n, i-chunk of 32):
// afrag stream = 32 KB FULLY CONTIGUOUS Wb. No LDS, no barriers.
// grid 1024 x 256 = 4096 waves.
__global__ __launch_bounds__(256) void caps_accum(
    const unsigned short* __restrict__ xb, const unsigned short* __restrict__ Wb,
    const unsigned short* __restrict__ Vb2, const float* __restrict__ denP,
    float* __restrict__ sPart)
{
  const int t = threadIdx.x, w = t >> 6, l = t & 63;
  const int m = l & 31, h = l >> 5;
  const int Wv = blockIdx.x * 4 + w;             // 0..4095
  const int n = Wv & 63, ch = Wv >> 6;
  const int i0 = ch * 32;
  const unsigned short* wrow = Wb + ((size_t)n * IC + i0) * 512 + l * 8;
  const unsigned short* xrow = xb + (size_t)i0 * 512 + l * 8;
  const unsigned short* vr = Vb2 + (size_t)n * 1024;
  f32x16 sacc = (f32x16)0.0f;
#pragma unroll 4
  for (int ii = 0; ii < 32; ++ii) {
    bf16x8 af = *reinterpret_cast<const bf16x8*>(wrow + (size_t)ii * 512);
    bf16x8 bf = *reinterpret_cast<const bf16x8*>(xrow + (size_t)ii * 512);
    f32x16 u = __builtin_amdgcn_mfma_f32_32x32x16_bf16(
        af, bf, (f32x16)0.0f, 0, 0, 0);
    // recompute e with the SAME dot sequence as caps_den (lane m = b)
    float partial = 0.f;
#pragma unroll
    for (int q = 0; q < 4; ++q) {
      uint2 vv = *reinterpret_cast<const uint2*>(vr + ((2*q+h) * 32 + m) * 4);
      partial += bflo(vv.x) * u[4*q+0] + bfhi(vv.x) * u[4*q+1]
               + bflo(vv.y) * u[4*q+2] + bfhi(vv.y) * u[4*q+3];
    }
    float logit = partial + __shfl_xor(partial, 32);
    float e = __expf(logit);
    float dp = denP[(size_t)(i0 + ii) * 64 + m]
             + denP[(size_t)(i0 + ii) * 64 + 32 + m];
    float c = e / dp;
#pragma unroll
    for (int k = 0; k < 16; ++k) sacc[k] += c * u[k];
  }
  float* page = sPart + ((size_t)n * 64 + ch) * 1024;
#pragma unroll
  for (int q = 0; q < 4; ++q) {
    float4 v = make_float4(sacc[4*q], sacc[4*q+1], sacc[4*q+2], sacc[4*q+3]);
    *reinterpret_cast<float4*>(page + ((2*q+h) * 32 + m) * 4) = v;
  }
}

// fused 64-page reduce + squash; emits V (f32), Vb2 (bf16) or out.
// 256 blocks (n x b-octet) x 64 thr; s2 reduce over dc via shfl_xor.
__global__ __launch_bounds__(64) void caps_redsq(
    const float4* __restrict__ sPart, float* __restrict__ V,
    unsigned short* __restrict__ Vb2, float* __restrict__ out, int mode)
{
  const int n = blockIdx.x >> 2, bq = blockIdx.x & 3;
  const int t = threadIdx.x;               // 64 = dc(8) x b8(8)
  const int dc = t >> 3, b8 = t & 7;
  const int b = bq * 8 + b8;
  const float4* base = sPart + (size_t)n * 64 * 256 + dc * 32 + b;
  float4 a = make_float4(0.f, 0.f, 0.f, 0.f);
#pragma unroll 8
  for (int ch = 0; ch < 64; ++ch) {
    float4 v = base[(size_t)ch * 256];
    a.x += v.x; a.y += v.y; a.z += v.z; a.w += v.w;
  }
  float s2 = a.x*a.x + a.y*a.y + a.z*a.z + a.w*a.w;
  s2 += __shfl_xor(s2, 8);
  s2 += __shfl_xor(s2, 16);
  s2 += __shfl_xor(s2, 32);
  float scale = s2 / ((1.0f + s2) * sqrtf(s2 + 1e-7f));
  float4 vd = make_float4(a.x*scale, a.y*scale, a.z*scale, a.w*scale);
  const size_t off = ((size_t)b * NC + n) * DD + dc * 4;   // V/out [b][n][d]
  if (mode == 2) {
    *reinterpret_cast<float4*>(out + off) = vd;
  } else {
    float4 nv = vd;
    if (mode == 1) {
      float4 old = *reinterpret_cast<const float4*>(V + off);
      nv.x += old.x; nv.y += old.y; nv.z += old.z; nv.w += old.w;
    }
    *reinterpret_cast<float4*>(V + off) = nv;
    uint2 pb;
    pb.x = pk2(nv.x, nv.y);
    pb.y = pk2(nv.z, nv.w);
    *reinterpret_cast<uint2*>(Vb2 + (size_t)n * 1024 + (dc * 32 + b) * 4) = pb;
  }
}

// ============================== fallback: R6 f32 path (ws too small) ========
__global__ void fb_zero(float* __restrict__ s) {
  s[blockIdx.x * 256 + threadIdx.x] = 0.0f;
}
__global__ __launch_bounds__(1024, 4)
void fb_pass(const float* __restrict__ x, const float* __restrict__ W,
             const float* __restrict__ V, float* __restrict__ sOut,
             float* __restrict__ sPart, int r, int usePart)
{
  const int t = threadIdx.x, w = t >> 6, l = t & 63;
  const int n = (w << 2) | (l >> 4);
  const int d0 = (l & 15) << 1;
  const int blk = blockIdx.x, xcd = blk & 7, slot = blk >> 3;
  const int ic = xcd * 8 + (slot >> 3), bq = slot & 7;
  const int i0 = ic * 32, bbase = bq * 4;
  __shared__ float den[2][4];
  __shared__ float Vlds[4 * NC * DD];
  if (r != 0) {
    const float4* src = reinterpret_cast<const float4*>(V + (size_t)bbase * 2048);
    float4* dst = reinterpret_cast<float4*>(Vlds);
    dst[t] = src[t]; dst[t + 1024] = src[t + 1024];
  }
  float acc0[4], acc1[4];
#pragma unroll
  for (int b = 0; b < 4; ++b) { acc0[b] = 0.f; acc1[b] = 0.f; }
  for (int ii = 0; ii < 32; ++ii) {
    const int i = i0 + ii, p = ii & 1;
    const float4* Wp = reinterpret_cast<const float4*>(
        W + (((size_t)n * IC + i) * DD + d0) * JD);
    float4 wr[8];
#pragma unroll
    for (int q = 0; q < 8; ++q) wr[q] = Wp[q];
    if (r == 0) {
#pragma unroll
      for (int bb = 0; bb < 4; ++bb) {
        const float* xp = x + ((size_t)(bbase + bb) * IC + i) * JD;
        float u0 = 0.f, u1 = 0.f;
#pragma unroll
        for (int q = 0; q < 4; ++q) {
          float4 w0 = wr[q], w1 = wr[4 + q];
          float x0 = xp[4*q], x1 = xp[4*q+1], x2 = xp[4*q+2], x3 = xp[4*q+3];
          u0 += w0.x*x0 + w0.y*x1 + w0.z*x2 + w0.w*x3;
          u1 += w1.x*x0 + w1.y*x1 + w1.z*x2 + w1.w*x3;
        }
        acc0[bb] += u0 * 0.015625f; acc1[bb] += u1 * 0.015625f;
      }
    } else {
      if (t < 4) den[p][t] = 0.0f;
      __syncthreads();
      float p0a[4], p1a[4];
#pragma unroll
      for (int bb = 0; bb < 4; ++bb) {
        const float* xp = x + ((size_t)(bbase + bb) * IC + i) * JD;
        float u0 = 0.f, u1 = 0.f;
#pragma unroll
        for (int q = 0; q < 4; ++q) {
          float4 w0 = wr[q], w1 = wr[4 + q];
          float x0 = xp[4*q], x1 = xp[4*q+1], x2 = xp[4*q+2], x3 = xp[4*q+3];
          u0 += w0.x*x0 + w0.y*x1 + w0.z*x2 + w0.w*x3;
          u1 += w1.x*x0 + w1.y*x1 + w1.z*x2 + w1.w*x3;
        }
        const float2 vv = *reinterpret_cast<const float2*>(
            &Vlds[((size_t)bb * NC + n) * DD + d0]);
        float lp = u0 * vv.x + u1 * vv.y;
        float logit = row16_sum(lp);
        float e = __expf(logit);
        p0a[bb] = e * u0; p1a[bb] = e * u1;
        float es = e + __shfl_xor(e, 16);
        es += __shfl_xor(es, 32);
        if (l == 0) atomicAdd(&den[p][bb], es);
      }
      __syncthreads();
#pragma unroll
      for (int bb = 0; bb < 4; ++bb) {
        float rd = 1.0f / den[p][bb];
        acc0[bb] += p0a[bb] * rd; acc1[bb] += p1a[bb] * rd;
      }
    }
  }
  if (usePart) {
#pragma unroll
    for (int bb = 0; bb < 4; ++bb) {
      float2 v2 = make_float2(acc0[bb], acc1[bb]);
      size_t off = (((size_t)(bq * 64 + ic) * 4 + bb) * NC + n) * DD + d0;
      *reinterpret_cast<float2*>(sPart + off) = v2;
    }
  } else {
#pragma unroll
    for (int bb = 0; bb < 4; ++bb) {
      float* sp = sOut + ((size_t)(bbase + bb) * NC + n) * DD + d0;
      atomicAdd(sp, acc0[bb]); atomicAdd(sp + 1, acc1[bb]);
    }
  }
}
__global__ void fb_reduceS(const float4* __restrict__ sPart, float4* __restrict__ s) {
  int q = blockIdx.x * 256 + threadIdx.x;
  int bq = q >> 11, qq = q & 2047;
  float4 sum = make_float4(0.f, 0.f, 0.f, 0.f);
#pragma unroll 8
  for (int p = 0; p < 64; ++p) {
    float4 v = sPart[(size_t)(bq * 64 + p) * 2048 + qq];
    sum.x += v.x; sum.y += v.y; sum.z += v.z; sum.w += v.w;
  }
  s[q] = sum;
}
__global__ void fb_squash(const float* __restrict__ s, float* __restrict__ V,
                          float* __restrict__ out, int mode)
{
  const int t = threadIdx.x;
  const int g = blockIdx.x * 8 + (t >> 5);
  const int d = t & 31;
  float v = s[(size_t)g * DD + d];
  float s2 = v * v;
#pragma unroll
  for (int off = 16; off; off >>= 1) s2 += __shfl_xor(s2, off);
  float scale = s2 / ((1.0f + s2) * sqrtf(s2 + 1e-7f));
  float vd = scale * v;
  if (mode == 2)      out[(size_t)g * DD + d] = vd;
  else if (mode == 0) V[(size_t)g * DD + d] = vd;
  else                V[(size_t)g * DD + d] += vd;
}

// ---------------------------------------------------------------------------
extern "C" void kernel_launch(void* const* d_in, const int* in_sizes, int n_in,
                              void* d_out, int out_size, void* d_ws, size_t ws_size,
                              hipStream_t stream) {
  const float* x = (const float*)d_in[0];
  const float* W = (const float*)d_in[1];
  float* out = (float*)d_out;
  char* ws = (char*)d_ws;
  // Wb 134217728 | xb 2097152 | denP 524288 | sPart 16777216 | V 262144
  // Vb2 131072  => 154009600
  const size_t NEED_NEW = 154009600ull;

  if (ws_size >= NEED_NEW) {
    unsigned short* Wb  = (unsigned short*)ws;
    unsigned short* xb  = (unsigned short*)(ws + 134217728);
    float* denP         = (float*)(ws + 136314880);
    float* sPart        = (float*)(ws + 136839168);
    float* V            = (float*)(ws + 153616384);
    unsigned short* Vb2 = (unsigned short*)(ws + 153878528);

    xb_conv<<<512, 256, 0, stream>>>(x, xb);
    caps_conv0<<<1024, 256, 0, stream>>>(xb, W, Wb, sPart);   // conv + round 0
    caps_redsq<<<256, 64, 0, stream>>>((const float4*)sPart, V, Vb2, out, 0);
    for (int r = 1; r < 3; ++r) {
      caps_den<<<1024, 256, 0, stream>>>(xb, Wb, Vb2, denP);
      caps_accum<<<1024, 256, 0, stream>>>(xb, Wb, Vb2, denP, sPart);
      caps_redsq<<<256, 64, 0, stream>>>((const float4*)sPart, V, Vb2, out,
                                         r == 2 ? 2 : 1);
    }
  } else {
    float* s     = (float*)ws;
    float* V     = s + 65536;
    float* sPart = V + 65536;
    const size_t need1 = (2ull * 65536 + 512ull * 8192) * 4;
    const int usePart = (ws_size >= need1) ? 1 : 0;
    for (int r = 0; r < 3; ++r) {
      if (!usePart) fb_zero<<<256, 256, 0, stream>>>(s);
      fb_pass<<<512, 1024, 0, stream>>>(x, W, V, s, sPart, r, usePart);
      if (usePart)
        fb_reduceS<<<64, 256, 0, stream>>>((const float4*)sPart, (float4*)s);
      fb_squash<<<256, 256, 0, stream>>>(s, V, out, r == 2 ? 2 : (r == 0 ? 0 : 1));
    }
  }
}